// Round 9
// baseline (487.916 us; speedup 1.0000x reference)
//
#include <hip/hip_runtime.h>
#include <cstdint>
#include <cstddef>

// ---- bf16 pack/unpack helpers (RNE) ----
static __device__ __forceinline__ unsigned int f2bf_rne(float f) {
    unsigned int u = __float_as_uint(f);
    unsigned int r = 0x7FFFu + ((u >> 16) & 1u);
    return (u + r) >> 16;
}
static __device__ __forceinline__ unsigned int pack_bf2(float lo, float hi) {
    return f2bf_rne(lo) | (f2bf_rne(hi) << 16);
}
static __device__ __forceinline__ float bf_lo(unsigned int w) {
    return __uint_as_float(w << 16);
}
static __device__ __forceinline__ float bf_hi(unsigned int w) {
    return __uint_as_float(w & 0xFFFF0000u);
}

#define BKT_CH 8192    // edges per chunk-block (fits LDS staging: 2x32KB)

// ---------------- CSR build ----------------
// R6 lesson: every per-edge GLOBAL atomic costs ~30B of HBM write traffic.
// Zero per-edge global atomics; bucket reservations LDS-aggregated; per-node
// counts/cursors in LDS of the single block owning each bucket.

__global__ void k_detect64(const unsigned int* ei, int e, int* is64) {
    __shared__ int nonzero;
    if (threadIdx.x == 0) nonzero = 0;
    __syncthreads();
    for (int i = threadIdx.x; i < 4096; i += blockDim.x) {
        size_t k = (size_t)((unsigned long long)i * (unsigned long long)e / 4096ull);
        if (ei[2 * k + 1] != 0u) nonzero = 1;   // racy OR, fine
    }
    __syncthreads();
    if (threadIdx.x == 0) *is64 = nonzero ? 0 : 1;
}

__global__ void k_zero512(int* p) { p[threadIdx.x] = 0; }

// Pass 0: bucket histogram (bucket = dst>>8). LDS-aggregated.
__global__ __launch_bounds__(256) void k_hist(const void* ei_raw, int e, const int* is64,
                                              int* __restrict__ bkt_cnt) {
    __shared__ int lcnt[512];
    int t = threadIdx.x;
    for (int j = t; j < 512; j += 256) lcnt[j] = 0;
    __syncthreads();
    int lo = blockIdx.x * BKT_CH;
    int hi = lo + BKT_CH; if (hi > e) hi = e;
    if (*is64) {
        const long long* p = (const long long*)ei_raw;
        for (int i = lo + t; i < hi; i += 256)
            atomicAdd(&lcnt[((int)p[(size_t)e + i]) >> 8], 1);
    } else {
        const int* p = (const int*)ei_raw;
        for (int i = lo + t; i < hi; i += 256)
            atomicAdd(&lcnt[p[(size_t)e + i] >> 8], 1);
    }
    __syncthreads();
    for (int j = t; j < 512; j += 256)
        if (lcnt[j]) atomicAdd(&bkt_cnt[j], lcnt[j]);
}

// Exclusive scan of bucket counts -> bkt_base[0..nb], bkt_cursor. One block.
__global__ __launch_bounds__(512) void k_scan_bkt(const int* __restrict__ bkt_cnt,
                                                  int* __restrict__ bkt_base,
                                                  int* __restrict__ bkt_cursor, int nb) {
    __shared__ int s[512];
    int t = threadIdx.x;
    int v = (t < nb) ? bkt_cnt[t] : 0;
    s[t] = v;
    __syncthreads();
    #pragma unroll
    for (int d = 1; d < 512; d <<= 1) {
        int tmp = (t >= d) ? s[t - d] : 0;
        __syncthreads();
        s[t] += tmp;
        __syncthreads();
    }
    if (t < nb) {
        int b = s[t] - v;
        bkt_base[t]   = b;
        bkt_cursor[t] = b;
    }
    if (t == 511) bkt_base[nb] = s[511];   // grand total (bins >= nb are 0)
}

// Pass 1: bucket the edges. One block per 8K-edge chunk; edges staged in LDS
// during the histogram pass (single global edge-list read), then scattered as
// packed u32 ((d&255)<<24 | src) at LDS-reserved offsets.
__global__ __launch_bounds__(256) void k_bucket(const void* ei_raw, int e, const int* is64,
                                                int* __restrict__ bkt_cursor,
                                                unsigned int* __restrict__ pout) {
    __shared__ int ldst[BKT_CH];
    __shared__ int lsrc[BKT_CH];
    __shared__ int lcnt[512];
    __shared__ int lbase[512];
    int t = threadIdx.x;
    int lo = blockIdx.x * BKT_CH;
    int hi = lo + BKT_CH; if (hi > e) hi = e;
    int m = hi - lo;
    for (int j = t; j < 512; j += 256) lcnt[j] = 0;
    __syncthreads();
    bool w64 = (*is64 != 0);
    const long long* p64 = (const long long*)ei_raw;
    const int*       p32 = (const int*)ei_raw;
    for (int idx = t; idx < m; idx += 256) {
        size_t i = (size_t)lo + idx;
        int s, d;
        if (w64) { s = (int)p64[i]; d = (int)p64[(size_t)e + i]; }
        else     { s = p32[i];      d = p32[(size_t)e + i]; }
        ldst[idx] = d;
        lsrc[idx] = s;
        atomicAdd(&lcnt[d >> 8], 1);
    }
    __syncthreads();
    for (int j = t; j < 512; j += 256) {
        int c = lcnt[j];
        lbase[j] = c ? atomicAdd(&bkt_cursor[j], c) : 0;
        lcnt[j] = 0;                        // running offset for scatter
    }
    __syncthreads();
    for (int idx = t; idx < m; idx += 256) {
        int d = ldst[idx], s = lsrc[idx];
        int b = d >> 8;
        int pos = lbase[b] + atomicAdd(&lcnt[b], 1);
        pout[pos] = ((unsigned int)(d & 255) << 24) | (unsigned int)s;
    }
}

// Pass 2: one block per bucket (256 nodes). Per-node counts in LDS -> local
// scan gives row_ptr + dinv (deg = cnt + 1 self-loop); LDS cursors scatter
// src into src_sorted. Single-block window -> full-line writebacks.
__global__ __launch_bounds__(256) void k_place_deg(const unsigned int* __restrict__ pairs,
                                                   const int* __restrict__ bkt_base,
                                                   int n, int nb,
                                                   int* __restrict__ row_ptr,
                                                   float* __restrict__ dinv,
                                                   int* __restrict__ src_sorted) {
    __shared__ int lcnt[256];
    __shared__ int ls[256];
    __shared__ int lcur[256];
    int b = blockIdx.x;
    int t = threadIdx.x;
    int base = bkt_base[b], end = bkt_base[b + 1];
    lcnt[t] = 0;
    __syncthreads();
    for (int i = base + t; i < end; i += 256)
        atomicAdd(&lcnt[__builtin_nontemporal_load(&pairs[i]) >> 24], 1);
    __syncthreads();
    int v = lcnt[t];
    ls[t] = v;
    __syncthreads();
    #pragma unroll
    for (int d = 1; d < 256; d <<= 1) {
        int tmp = (t >= d) ? ls[t - d] : 0;
        __syncthreads();
        ls[t] += tmp;
        __syncthreads();
    }
    int nodebase = base + ls[t] - v;       // exclusive within bucket
    int node = (b << 8) + t;
    if (node < n) {
        row_ptr[node] = nodebase;
        dinv[node] = rsqrtf((float)(v + 1));
    }
    lcur[t] = nodebase;
    __syncthreads();
    for (int i = base + t; i < end; i += 256) {
        unsigned int pr = __builtin_nontemporal_load(&pairs[i]);
        int pos = atomicAdd(&lcur[pr >> 24], 1);
        src_sorted[pos] = (int)(pr & 0x00FFFFFFu);
    }
    if (t == 0 && b == nb - 1) row_ptr[n] = end;
}

// ---------------- Layer-1 GEMM (f32 VALU, LDS-tiled) ----------------
// hsb[m][c/2] = pack_bf16( dinv[m] * (x[m]@W1)[c..c+1] ), K=128, N=128.
// bf16 pack halves downstream gather bytes (R3: agg was L3-service-bound).
__global__ __launch_bounds__(256) void k_gemm128(const float* __restrict__ A,
                                                 const float* __restrict__ W,
                                                 const float* __restrict__ dinv,
                                                 unsigned int* __restrict__ hsb, int M) {
    __shared__ float sA[64][36];
    __shared__ float sW[32][128];
    int tid = threadIdx.x;
    int tx = tid & 15;   // cols tx*8 .. +7
    int ty = tid >> 4;   // rows ty*4 .. +3
    int row0 = blockIdx.x * 64;
    float acc[4][8] = {};
    for (int k0 = 0; k0 < 128; k0 += 32) {
        __syncthreads();
        for (int i = tid; i < 512; i += 256) {
            int r = i >> 3, c4 = i & 7;
            float4 v = {0.f, 0.f, 0.f, 0.f};
            int gr = row0 + r;
            if (gr < M) v = *reinterpret_cast<const float4*>(&A[(size_t)gr * 128 + k0 + c4 * 4]);
            *reinterpret_cast<float4*>(&sA[r][c4 * 4]) = v;
        }
        for (int i = tid; i < 1024; i += 256) {
            int r = i >> 5, c4 = i & 31;
            *reinterpret_cast<float4*>(&sW[r][c4 * 4]) =
                *reinterpret_cast<const float4*>(&W[(size_t)(k0 + r) * 128 + c4 * 4]);
        }
        __syncthreads();
        #pragma unroll
        for (int k = 0; k < 32; k += 4) {
            float4 a[4];
            #pragma unroll
            for (int r = 0; r < 4; ++r)
                a[r] = *reinterpret_cast<const float4*>(&sA[ty * 4 + r][k]);
            #pragma unroll
            for (int kk = 0; kk < 4; ++kk) {
                float4 w0 = *reinterpret_cast<const float4*>(&sW[k + kk][tx * 8]);
                float4 w1 = *reinterpret_cast<const float4*>(&sW[k + kk][tx * 8 + 4]);
                #pragma unroll
                for (int r = 0; r < 4; ++r) {
                    float av = (&a[r].x)[kk];
                    acc[r][0] += av * w0.x; acc[r][1] += av * w0.y;
                    acc[r][2] += av * w0.z; acc[r][3] += av * w0.w;
                    acc[r][4] += av * w1.x; acc[r][5] += av * w1.y;
                    acc[r][6] += av * w1.z; acc[r][7] += av * w1.w;
                }
            }
        }
    }
    #pragma unroll
    for (int r = 0; r < 4; ++r) {
        int gr = row0 + ty * 4 + r;
        if (gr < M) {
            float di = dinv[gr];
            uint4 o;
            o.x = pack_bf2(acc[r][0] * di, acc[r][1] * di);
            o.y = pack_bf2(acc[r][2] * di, acc[r][3] * di);
            o.z = pack_bf2(acc[r][4] * di, acc[r][5] * di);
            o.w = pack_bf2(acc[r][6] * di, acc[r][7] * di);
            *reinterpret_cast<uint4*>(&hsb[(size_t)gr * 64 + tx * 4]) = o;
        }
    }
}

// ---------------- Fused agg1 + gemm64 ----------------
// R9: kills the h2 global round-trip (25.6MB write + 25.6MB read) and a
// launch. Block = 256 threads owns 64 nodes. Phase 1: 4 waves gather/relu
// 16 nodes each into LDS h2s (f32). Phase 2: z = h2@W2 from LDS, epilogue
// packs dinv-scaled bf16 into zsb. Gather-phase blocks (mem-bound) and
// GEMM-phase blocks (VALU) co-schedule per CU -> GEMM mostly hidden.
__global__ __launch_bounds__(256) void k_fused1(const unsigned int* __restrict__ hsb,
                                                const float* __restrict__ dinv,
                                                const int* __restrict__ row_ptr,
                                                const int* __restrict__ src_sorted,
                                                const float* __restrict__ b1,
                                                const float* __restrict__ W2,
                                                unsigned int* __restrict__ zsb, int n) {
    __shared__ float h2s[64][132];   // 132: float4-aligned rows, bank-spread
    __shared__ float sW[32][64];
    int tid = threadIdx.x;
    int w   = tid >> 6;          // wave 0..3
    int c   = tid & 63;          // channel pair 2c, 2c+1
    int row0 = blockIdx.x * 64;

    // ---- Phase 1: gather + bias + relu -> LDS (f32) ----
    float2 bb = *reinterpret_cast<const float2*>(&b1[2 * c]);
    for (int j = 0; j < 16; ++j) {
        int il = w * 16 + j;
        int i  = row0 + il;
        float v0 = 0.f, v1 = 0.f;
        if (i < n) {
            unsigned int wd = hsb[(size_t)i * 64 + c];
            float ax = bf_lo(wd), ay = bf_hi(wd);
            int lo = row_ptr[i], hi = row_ptr[i + 1];
            int e = lo;
            for (; e + 8 <= hi; e += 8) {
                int s0 = __builtin_nontemporal_load(&src_sorted[e + 0]);
                int s1 = __builtin_nontemporal_load(&src_sorted[e + 1]);
                int s2 = __builtin_nontemporal_load(&src_sorted[e + 2]);
                int s3 = __builtin_nontemporal_load(&src_sorted[e + 3]);
                int s4 = __builtin_nontemporal_load(&src_sorted[e + 4]);
                int s5 = __builtin_nontemporal_load(&src_sorted[e + 5]);
                int s6 = __builtin_nontemporal_load(&src_sorted[e + 6]);
                int s7 = __builtin_nontemporal_load(&src_sorted[e + 7]);
                unsigned int w0 = hsb[(size_t)s0 * 64 + c];
                unsigned int w1 = hsb[(size_t)s1 * 64 + c];
                unsigned int w2 = hsb[(size_t)s2 * 64 + c];
                unsigned int w3 = hsb[(size_t)s3 * 64 + c];
                unsigned int w4 = hsb[(size_t)s4 * 64 + c];
                unsigned int w5 = hsb[(size_t)s5 * 64 + c];
                unsigned int w6 = hsb[(size_t)s6 * 64 + c];
                unsigned int w7 = hsb[(size_t)s7 * 64 + c];
                ax += ((bf_lo(w0) + bf_lo(w1)) + (bf_lo(w2) + bf_lo(w3)))
                    + ((bf_lo(w4) + bf_lo(w5)) + (bf_lo(w6) + bf_lo(w7)));
                ay += ((bf_hi(w0) + bf_hi(w1)) + (bf_hi(w2) + bf_hi(w3)))
                    + ((bf_hi(w4) + bf_hi(w5)) + (bf_hi(w6) + bf_hi(w7)));
            }
            if (e + 4 <= hi) {
                int s0 = __builtin_nontemporal_load(&src_sorted[e + 0]);
                int s1 = __builtin_nontemporal_load(&src_sorted[e + 1]);
                int s2 = __builtin_nontemporal_load(&src_sorted[e + 2]);
                int s3 = __builtin_nontemporal_load(&src_sorted[e + 3]);
                unsigned int w0 = hsb[(size_t)s0 * 64 + c];
                unsigned int w1 = hsb[(size_t)s1 * 64 + c];
                unsigned int w2 = hsb[(size_t)s2 * 64 + c];
                unsigned int w3 = hsb[(size_t)s3 * 64 + c];
                ax += (bf_lo(w0) + bf_lo(w1)) + (bf_lo(w2) + bf_lo(w3));
                ay += (bf_hi(w0) + bf_hi(w1)) + (bf_hi(w2) + bf_hi(w3));
                e += 4;
            }
            for (; e < hi; ++e) {
                int s = __builtin_nontemporal_load(&src_sorted[e]);
                unsigned int ws = hsb[(size_t)s * 64 + c];
                ax += bf_lo(ws);
                ay += bf_hi(ws);
            }
            float di = dinv[i];
            v0 = di * ax + bb.x;
            v1 = di * ay + bb.y;
            v0 = v0 > 0.f ? v0 : 0.f;
            v1 = v1 > 0.f ? v1 : 0.f;
        }
        float2 o = {v0, v1};
        *reinterpret_cast<float2*>(&h2s[il][2 * c]) = o;
    }
    __syncthreads();

    // ---- Phase 2: z = h2 @ W2 (K=128, N=64) from LDS ----
    int tx = tid & 15;   // cols tx*4 .. +3
    int ty = tid >> 4;   // rows ty*4 .. +3
    float acc[4][4] = {};
    for (int k0 = 0; k0 < 128; k0 += 32) {
        __syncthreads();
        for (int i = tid; i < 512; i += 256) {
            int r = i >> 4, c4 = i & 15;
            *reinterpret_cast<float4*>(&sW[r][c4 * 4]) =
                *reinterpret_cast<const float4*>(&W2[(size_t)(k0 + r) * 64 + c4 * 4]);
        }
        __syncthreads();
        #pragma unroll
        for (int k = 0; k < 32; k += 4) {
            float4 a[4];
            #pragma unroll
            for (int r = 0; r < 4; ++r)
                a[r] = *reinterpret_cast<const float4*>(&h2s[ty * 4 + r][k0 + k]);
            #pragma unroll
            for (int kk = 0; kk < 4; ++kk) {
                float4 wv = *reinterpret_cast<const float4*>(&sW[k + kk][tx * 4]);
                #pragma unroll
                for (int r = 0; r < 4; ++r) {
                    float av = (&a[r].x)[kk];
                    acc[r][0] += av * wv.x; acc[r][1] += av * wv.y;
                    acc[r][2] += av * wv.z; acc[r][3] += av * wv.w;
                }
            }
        }
    }
    #pragma unroll
    for (int r = 0; r < 4; ++r) {
        int gr = row0 + ty * 4 + r;
        if (gr < n) {
            float di = dinv[gr];
            uint2 o;
            o.x = pack_bf2(acc[r][0] * di, acc[r][1] * di);
            o.y = pack_bf2(acc[r][2] * di, acc[r][3] * di);
            *reinterpret_cast<uint2*>(&zsb[(size_t)gr * 32 + tx * 2]) = o;
        }
    }
}

// ---------------- Layer-2 aggregation ----------------
// out[i][2c..2c+1] = dinv[i]*(zsb_sum) + b2; 2 nodes per 64-thread block.
__global__ __launch_bounds__(64) void k_agg2(const unsigned int* __restrict__ zsb,
                                             const float* __restrict__ dinv,
                                             const int* __restrict__ row_ptr,
                                             const int* __restrict__ src_sorted,
                                             const float* __restrict__ b2,
                                             float* __restrict__ out, int n) {
    int i = blockIdx.x * 2 + (threadIdx.x >> 5);
    int c = threadIdx.x & 31;     // channel pair 2c, 2c+1
    if (i >= n) return;
    unsigned int w = zsb[(size_t)i * 32 + c];
    float ax = bf_lo(w), ay = bf_hi(w);
    int lo = row_ptr[i], hi = row_ptr[i + 1];
    int e = lo;
    for (; e + 8 <= hi; e += 8) {
        int s0 = __builtin_nontemporal_load(&src_sorted[e + 0]);
        int s1 = __builtin_nontemporal_load(&src_sorted[e + 1]);
        int s2 = __builtin_nontemporal_load(&src_sorted[e + 2]);
        int s3 = __builtin_nontemporal_load(&src_sorted[e + 3]);
        int s4 = __builtin_nontemporal_load(&src_sorted[e + 4]);
        int s5 = __builtin_nontemporal_load(&src_sorted[e + 5]);
        int s6 = __builtin_nontemporal_load(&src_sorted[e + 6]);
        int s7 = __builtin_nontemporal_load(&src_sorted[e + 7]);
        unsigned int w0 = zsb[(size_t)s0 * 32 + c];
        unsigned int w1 = zsb[(size_t)s1 * 32 + c];
        unsigned int w2 = zsb[(size_t)s2 * 32 + c];
        unsigned int w3 = zsb[(size_t)s3 * 32 + c];
        unsigned int w4 = zsb[(size_t)s4 * 32 + c];
        unsigned int w5 = zsb[(size_t)s5 * 32 + c];
        unsigned int w6 = zsb[(size_t)s6 * 32 + c];
        unsigned int w7 = zsb[(size_t)s7 * 32 + c];
        ax += ((bf_lo(w0) + bf_lo(w1)) + (bf_lo(w2) + bf_lo(w3)))
            + ((bf_lo(w4) + bf_lo(w5)) + (bf_lo(w6) + bf_lo(w7)));
        ay += ((bf_hi(w0) + bf_hi(w1)) + (bf_hi(w2) + bf_hi(w3)))
            + ((bf_hi(w4) + bf_hi(w5)) + (bf_hi(w6) + bf_hi(w7)));
    }
    if (e + 4 <= hi) {
        int s0 = __builtin_nontemporal_load(&src_sorted[e + 0]);
        int s1 = __builtin_nontemporal_load(&src_sorted[e + 1]);
        int s2 = __builtin_nontemporal_load(&src_sorted[e + 2]);
        int s3 = __builtin_nontemporal_load(&src_sorted[e + 3]);
        unsigned int w0 = zsb[(size_t)s0 * 32 + c];
        unsigned int w1 = zsb[(size_t)s1 * 32 + c];
        unsigned int w2 = zsb[(size_t)s2 * 32 + c];
        unsigned int w3 = zsb[(size_t)s3 * 32 + c];
        ax += (bf_lo(w0) + bf_lo(w1)) + (bf_lo(w2) + bf_lo(w3));
        ay += (bf_hi(w0) + bf_hi(w1)) + (bf_hi(w2) + bf_hi(w3));
        e += 4;
    }
    for (; e < hi; ++e) {
        int s = __builtin_nontemporal_load(&src_sorted[e]);
        unsigned int ws = zsb[(size_t)s * 32 + c];
        ax += bf_lo(ws);
        ay += bf_hi(ws);
    }
    float di = dinv[i];
    float2 bb = *reinterpret_cast<const float2*>(&b2[2 * c]);
    float2 o = {di * ax + bb.x, di * ay + bb.y};
    *reinterpret_cast<float2*>(&out[(size_t)i * 64 + 2 * c]) = o;
}

// ---------------- launch ----------------

static inline size_t alignup(size_t v) { return (v + 255) & ~(size_t)255; }

extern "C" void kernel_launch(void* const* d_in, const int* in_sizes, int n_in,
                              void* d_out, int out_size, void* d_ws, size_t ws_size,
                              hipStream_t stream) {
    const float* x  = (const float*)d_in[0];
    const void*  ei = d_in[1];
    const float* W1 = (const float*)d_in[2];
    const float* b1 = (const float*)d_in[3];
    const float* W2 = (const float*)d_in[4];
    const float* b2 = (const float*)d_in[5];

    const int n = in_sizes[0] / 128;   // 100000
    const int e = in_sizes[1] / 2;     // 3200000

    // Region aliasing: packed pairs (u32, 12.8 MB) are dead before k_gemm128
    // writes hsb (stream-ordered), so they share one region.
    char* p = (char*)d_ws;
    auto take = [&](size_t bytes) { char* q = p; p += alignup(bytes); return q; };
    size_t pairs_bytes = (size_t)e * 4;            // 12.8 MB
    size_t hsb_bytes   = (size_t)n * 64 * 4;       // 25.6 MB
    size_t regA_bytes  = pairs_bytes > hsb_bytes ? pairs_bytes : hsb_bytes;
    char* regA = (char*)take(regA_bytes);
    unsigned int* pairs = (unsigned int*)regA;
    unsigned int* hsb   = (unsigned int*)regA;

    int*          is64       = (int*)  take(4);
    float*        dinv       = (float*)take((size_t)n * 4);
    int*          row_ptr    = (int*)  take((size_t)(n + 1) * 4);
    int*          bkt_cnt    = (int*)  take(512 * 4);
    int*          bkt_base   = (int*)  take(513 * 4);
    int*          bkt_cursor = (int*)  take(512 * 4);
    int*          src_sorted = (int*)  take((size_t)e * 4);
    unsigned int* zsb        = (unsigned int*)take((size_t)n * 32 * 4);
    if ((size_t)(p - (char*)d_ws) > ws_size) return;  // ws too small -> fail loudly

    const int nb_bkt  = (n + 255) >> 8;             // 391 buckets of 256 nodes
    const int nb_chnk = (e + BKT_CH - 1) / BKT_CH;  // 391 chunks

    k_detect64<<<1, 256, 0, stream>>>((const unsigned int*)ei, e, is64);
    k_zero512<<<1, 512, 0, stream>>>(bkt_cnt);
    k_hist<<<nb_chnk, 256, 0, stream>>>(ei, e, is64, bkt_cnt);
    k_scan_bkt<<<1, 512, 0, stream>>>(bkt_cnt, bkt_base, bkt_cursor, nb_bkt);
    k_bucket<<<nb_chnk, 256, 0, stream>>>(ei, e, is64, bkt_cursor, pairs);
    k_place_deg<<<nb_bkt, 256, 0, stream>>>(pairs, bkt_base, n, nb_bkt,
                                            row_ptr, dinv, src_sorted);

    k_gemm128<<<(n + 63) / 64, 256, 0, stream>>>(x, W1, dinv, hsb, n);
    k_fused1<<<(n + 63) / 64, 256, 0, stream>>>(hsb, dinv, row_ptr, src_sorted,
                                                b1, W2, zsb, n);
    k_agg2<<<(n + 1) / 2, 64, 0, stream>>>(zsb, dinv, row_ptr, src_sorted, b2, (float*)d_out, n);
}

// Round 10
// 320.400 us; speedup vs baseline: 1.5228x; 1.5228x over previous
//
#include <hip/hip_runtime.h>
#include <cstdint>
#include <cstddef>

typedef short bf16x8 __attribute__((ext_vector_type(8)));
typedef float f32x4  __attribute__((ext_vector_type(4)));

// ---- bf16 pack/unpack helpers (RNE) ----
static __device__ __forceinline__ unsigned int f2bf_rne(float f) {
    unsigned int u = __float_as_uint(f);
    unsigned int r = 0x7FFFu + ((u >> 16) & 1u);
    return (u + r) >> 16;
}
static __device__ __forceinline__ unsigned int pack_bf2(float lo, float hi) {
    return f2bf_rne(lo) | (f2bf_rne(hi) << 16);
}
static __device__ __forceinline__ float bf_lo(unsigned int w) {
    return __uint_as_float(w << 16);
}
static __device__ __forceinline__ float bf_hi(unsigned int w) {
    return __uint_as_float(w & 0xFFFF0000u);
}

#define BKT_CH 8192    // edges per chunk-block (fits LDS staging: 2x32KB)

// ---------------- CSR build (R6-R8: zero per-edge global atomics) ----------------

__global__ void k_detect64(const unsigned int* ei, int e, int* is64) {
    __shared__ int nonzero;
    if (threadIdx.x == 0) nonzero = 0;
    __syncthreads();
    for (int i = threadIdx.x; i < 4096; i += blockDim.x) {
        size_t k = (size_t)((unsigned long long)i * (unsigned long long)e / 4096ull);
        if (ei[2 * k + 1] != 0u) nonzero = 1;   // racy OR, fine
    }
    __syncthreads();
    if (threadIdx.x == 0) *is64 = nonzero ? 0 : 1;
}

__global__ void k_zero512(int* p) { p[threadIdx.x] = 0; }

__global__ __launch_bounds__(256) void k_hist(const void* ei_raw, int e, const int* is64,
                                              int* __restrict__ bkt_cnt) {
    __shared__ int lcnt[512];
    int t = threadIdx.x;
    for (int j = t; j < 512; j += 256) lcnt[j] = 0;
    __syncthreads();
    int lo = blockIdx.x * BKT_CH;
    int hi = lo + BKT_CH; if (hi > e) hi = e;
    if (*is64) {
        const long long* p = (const long long*)ei_raw;
        for (int i = lo + t; i < hi; i += 256)
            atomicAdd(&lcnt[((int)p[(size_t)e + i]) >> 8], 1);
    } else {
        const int* p = (const int*)ei_raw;
        for (int i = lo + t; i < hi; i += 256)
            atomicAdd(&lcnt[p[(size_t)e + i] >> 8], 1);
    }
    __syncthreads();
    for (int j = t; j < 512; j += 256)
        if (lcnt[j]) atomicAdd(&bkt_cnt[j], lcnt[j]);
}

__global__ __launch_bounds__(512) void k_scan_bkt(const int* __restrict__ bkt_cnt,
                                                  int* __restrict__ bkt_base,
                                                  int* __restrict__ bkt_cursor, int nb) {
    __shared__ int s[512];
    int t = threadIdx.x;
    int v = (t < nb) ? bkt_cnt[t] : 0;
    s[t] = v;
    __syncthreads();
    #pragma unroll
    for (int d = 1; d < 512; d <<= 1) {
        int tmp = (t >= d) ? s[t - d] : 0;
        __syncthreads();
        s[t] += tmp;
        __syncthreads();
    }
    if (t < nb) {
        int b = s[t] - v;
        bkt_base[t]   = b;
        bkt_cursor[t] = b;
    }
    if (t == 511) bkt_base[nb] = s[511];
}

__global__ __launch_bounds__(256) void k_bucket(const void* ei_raw, int e, const int* is64,
                                                int* __restrict__ bkt_cursor,
                                                unsigned int* __restrict__ pout) {
    __shared__ int ldst[BKT_CH];
    __shared__ int lsrc[BKT_CH];
    __shared__ int lcnt[512];
    __shared__ int lbase[512];
    int t = threadIdx.x;
    int lo = blockIdx.x * BKT_CH;
    int hi = lo + BKT_CH; if (hi > e) hi = e;
    int m = hi - lo;
    for (int j = t; j < 512; j += 256) lcnt[j] = 0;
    __syncthreads();
    bool w64 = (*is64 != 0);
    const long long* p64 = (const long long*)ei_raw;
    const int*       p32 = (const int*)ei_raw;
    for (int idx = t; idx < m; idx += 256) {
        size_t i = (size_t)lo + idx;
        int s, d;
        if (w64) { s = (int)p64[i]; d = (int)p64[(size_t)e + i]; }
        else     { s = p32[i];      d = p32[(size_t)e + i]; }
        ldst[idx] = d;
        lsrc[idx] = s;
        atomicAdd(&lcnt[d >> 8], 1);
    }
    __syncthreads();
    for (int j = t; j < 512; j += 256) {
        int c = lcnt[j];
        lbase[j] = c ? atomicAdd(&bkt_cursor[j], c) : 0;
        lcnt[j] = 0;
    }
    __syncthreads();
    for (int idx = t; idx < m; idx += 256) {
        int d = ldst[idx], s = lsrc[idx];
        int b = d >> 8;
        int pos = lbase[b] + atomicAdd(&lcnt[b], 1);
        pout[pos] = ((unsigned int)(d & 255) << 24) | (unsigned int)s;
    }
}

__global__ __launch_bounds__(256) void k_place_deg(const unsigned int* __restrict__ pairs,
                                                   const int* __restrict__ bkt_base,
                                                   int n, int nb,
                                                   int* __restrict__ row_ptr,
                                                   float* __restrict__ dinv,
                                                   int* __restrict__ src_sorted) {
    __shared__ int lcnt[256];
    __shared__ int ls[256];
    __shared__ int lcur[256];
    int b = blockIdx.x;
    int t = threadIdx.x;
    int base = bkt_base[b], end = bkt_base[b + 1];
    lcnt[t] = 0;
    __syncthreads();
    for (int i = base + t; i < end; i += 256)
        atomicAdd(&lcnt[__builtin_nontemporal_load(&pairs[i]) >> 24], 1);
    __syncthreads();
    int v = lcnt[t];
    ls[t] = v;
    __syncthreads();
    #pragma unroll
    for (int d = 1; d < 256; d <<= 1) {
        int tmp = (t >= d) ? ls[t - d] : 0;
        __syncthreads();
        ls[t] += tmp;
        __syncthreads();
    }
    int nodebase = base + ls[t] - v;
    int node = (b << 8) + t;
    if (node < n) {
        row_ptr[node] = nodebase;
        dinv[node] = rsqrtf((float)(v + 1));
    }
    lcur[t] = nodebase;
    __syncthreads();
    for (int i = base + t; i < end; i += 256) {
        unsigned int pr = __builtin_nontemporal_load(&pairs[i]);
        int pos = atomicAdd(&lcur[pr >> 24], 1);
        src_sorted[pos] = (int)(pr & 0x00FFFFFFu);
    }
    if (t == 0 && b == nb - 1) row_ptr[n] = end;
}

// ---------------- Layer-1 GEMM: MFMA bf16 16x16x32 ----------------
// hsb[m][c/2] = pack_bf16(dinv[m] * (x[m]@W1)[c..c+1]), M-tile 64, N=128, K=128.
// x converted f32->bf16 during LDS staging. 4 waves: wave w owns rows w*16..+15.
// A_lds padded to stride 68 u32 (row*272B: banks spread, 16B-aligned).
__global__ __launch_bounds__(256) void k_gemm128(const float* __restrict__ A,
                                                 const float* __restrict__ W,
                                                 const float* __restrict__ dinv,
                                                 unsigned int* __restrict__ hsb, int M) {
    __shared__ unsigned int A_lds[64][68];       // bf16x2 words, k-major
    __shared__ unsigned int B_lds[16 * 128 * 4]; // [kg][col][j2]: 8 bf16 per (kg,col)
    int tid = threadIdx.x;
    int w   = tid >> 6;
    int l   = tid & 63;
    int row0 = blockIdx.x * 64;

    // stage A: 64 rows x 128 k (f32 -> bf16x2), coalesced float2 reads
    for (int idx = tid; idx < 4096; idx += 256) {
        int r = idx >> 6, kp = idx & 63;
        unsigned int pv = 0u;
        int gr = row0 + r;
        if (gr < M) {
            float2 f = *reinterpret_cast<const float2*>(&A[(size_t)gr * 128 + 2 * kp]);
            pv = pack_bf2(f.x, f.y);
        }
        A_lds[r][kp] = pv;
    }
    // stage B: W[128][128] f32 -> k-packed bf16 (kg = k/8, j2 = (k/2)%4)
    for (int idx = tid; idx < 8192; idx += 256) {
        int col = idx & 127, kp = idx >> 7;
        float v0 = W[(size_t)(2 * kp) * 128 + col];
        float v1 = W[(size_t)(2 * kp + 1) * 128 + col];
        B_lds[(((kp >> 2) * 128) + col) * 4 + (kp & 3)] = pack_bf2(v0, v1);
    }
    __syncthreads();

    int arow = w * 16 + (l & 15);
    int kq   = (l >> 4);                 // 0..3: k-subgroup of 8
    f32x4 acc[8];
    #pragma unroll
    for (int nb = 0; nb < 8; ++nb) acc[nb] = (f32x4){0.f, 0.f, 0.f, 0.f};

    #pragma unroll
    for (int k0 = 0; k0 < 4; ++k0) {     // k = k0*32
        bf16x8 af = *reinterpret_cast<const bf16x8*>(&A_lds[arow][k0 * 16 + kq * 4]);
        #pragma unroll
        for (int nb = 0; nb < 8; ++nb) {
            const unsigned int* bp = &B_lds[(((k0 * 4 + kq) * 128) + nb * 16 + (l & 15)) * 4];
            bf16x8 bf = *reinterpret_cast<const bf16x8*>(bp);
            acc[nb] = __builtin_amdgcn_mfma_f32_16x16x32_bf16(af, bf, acc[nb], 0, 0, 0);
        }
    }

    // epilogue: D col = l&15, row = (l>>4)*4 + r; pack bf16 pairs via shfl
    #pragma unroll
    for (int r = 0; r < 4; ++r) {
        int gr = row0 + w * 16 + (l >> 4) * 4 + r;
        float di = (gr < M) ? dinv[gr] : 0.f;
        #pragma unroll
        for (int nb = 0; nb < 8; ++nb) {
            float fv = acc[nb][r] * di;
            float pv = __shfl_xor(fv, 1);
            if ((l & 1) == 0 && gr < M) {
                hsb[(size_t)gr * 64 + nb * 8 + ((l & 15) >> 1)] = pack_bf2(fv, pv);
            }
        }
    }
}

// ---------------- Layer-2 GEMM: MFMA bf16 16x16x32 ----------------
// zsb[m][c/2] = pack_bf16(dinv[m] * (h2b[m]@W2)[c..c+1]), N=64, K=128.
// A (h2b) is already bf16x2-packed -> staged as straight u32 copies.
__global__ __launch_bounds__(256) void k_gemm64(const unsigned int* __restrict__ Ab,
                                                const float* __restrict__ W,
                                                const float* __restrict__ dinv,
                                                unsigned int* __restrict__ zsb, int M) {
    __shared__ unsigned int A_lds[64][68];
    __shared__ unsigned int B_lds[16 * 64 * 4];
    int tid = threadIdx.x;
    int w   = tid >> 6;
    int l   = tid & 63;
    int row0 = blockIdx.x * 64;

    for (int idx = tid; idx < 4096; idx += 256) {
        int r = idx >> 6, kp = idx & 63;
        int gr = row0 + r;
        A_lds[r][kp] = (gr < M) ? Ab[(size_t)gr * 64 + kp] : 0u;
    }
    for (int idx = tid; idx < 4096; idx += 256) {
        int col = idx & 63, kp = idx >> 6;
        float v0 = W[(size_t)(2 * kp) * 64 + col];
        float v1 = W[(size_t)(2 * kp + 1) * 64 + col];
        B_lds[(((kp >> 2) * 64) + col) * 4 + (kp & 3)] = pack_bf2(v0, v1);
    }
    __syncthreads();

    int arow = w * 16 + (l & 15);
    int kq   = (l >> 4);
    f32x4 acc[4];
    #pragma unroll
    for (int nb = 0; nb < 4; ++nb) acc[nb] = (f32x4){0.f, 0.f, 0.f, 0.f};

    #pragma unroll
    for (int k0 = 0; k0 < 4; ++k0) {
        bf16x8 af = *reinterpret_cast<const bf16x8*>(&A_lds[arow][k0 * 16 + kq * 4]);
        #pragma unroll
        for (int nb = 0; nb < 4; ++nb) {
            const unsigned int* bp = &B_lds[(((k0 * 4 + kq) * 64) + nb * 16 + (l & 15)) * 4];
            bf16x8 bf = *reinterpret_cast<const bf16x8*>(bp);
            acc[nb] = __builtin_amdgcn_mfma_f32_16x16x32_bf16(af, bf, acc[nb], 0, 0, 0);
        }
    }

    #pragma unroll
    for (int r = 0; r < 4; ++r) {
        int gr = row0 + w * 16 + (l >> 4) * 4 + r;
        float di = (gr < M) ? dinv[gr] : 0.f;
        #pragma unroll
        for (int nb = 0; nb < 4; ++nb) {
            float fv = acc[nb][r] * di;
            float pv = __shfl_xor(fv, 1);
            if ((l & 1) == 0 && gr < M) {
                zsb[(size_t)gr * 32 + nb * 8 + ((l & 15) >> 1)] = pack_bf2(fv, pv);
            }
        }
    }
}

// ---------------- Aggregation (R8 config: high occupancy, x8 unroll) ----------------

// h2b[i][c] = pack_bf16(relu(dinv[i]*sum + b1[2c..2c+1])), one wave per node.
__global__ __launch_bounds__(64) void k_agg1(const unsigned int* __restrict__ hsb,
                                             const float* __restrict__ dinv,
                                             const int* __restrict__ row_ptr,
                                             const int* __restrict__ src_sorted,
                                             const float* __restrict__ b1,
                                             unsigned int* __restrict__ h2b) {
    int i = blockIdx.x;
    int c = threadIdx.x;
    unsigned int w = hsb[(size_t)i * 64 + c];
    float ax = bf_lo(w), ay = bf_hi(w);
    int lo = row_ptr[i], hi = row_ptr[i + 1];
    int e = lo;
    for (; e + 8 <= hi; e += 8) {
        int s0 = __builtin_nontemporal_load(&src_sorted[e + 0]);
        int s1 = __builtin_nontemporal_load(&src_sorted[e + 1]);
        int s2 = __builtin_nontemporal_load(&src_sorted[e + 2]);
        int s3 = __builtin_nontemporal_load(&src_sorted[e + 3]);
        int s4 = __builtin_nontemporal_load(&src_sorted[e + 4]);
        int s5 = __builtin_nontemporal_load(&src_sorted[e + 5]);
        int s6 = __builtin_nontemporal_load(&src_sorted[e + 6]);
        int s7 = __builtin_nontemporal_load(&src_sorted[e + 7]);
        unsigned int w0 = hsb[(size_t)s0 * 64 + c];
        unsigned int w1 = hsb[(size_t)s1 * 64 + c];
        unsigned int w2 = hsb[(size_t)s2 * 64 + c];
        unsigned int w3 = hsb[(size_t)s3 * 64 + c];
        unsigned int w4 = hsb[(size_t)s4 * 64 + c];
        unsigned int w5 = hsb[(size_t)s5 * 64 + c];
        unsigned int w6 = hsb[(size_t)s6 * 64 + c];
        unsigned int w7 = hsb[(size_t)s7 * 64 + c];
        ax += ((bf_lo(w0) + bf_lo(w1)) + (bf_lo(w2) + bf_lo(w3)))
            + ((bf_lo(w4) + bf_lo(w5)) + (bf_lo(w6) + bf_lo(w7)));
        ay += ((bf_hi(w0) + bf_hi(w1)) + (bf_hi(w2) + bf_hi(w3)))
            + ((bf_hi(w4) + bf_hi(w5)) + (bf_hi(w6) + bf_hi(w7)));
    }
    if (e + 4 <= hi) {
        int s0 = __builtin_nontemporal_load(&src_sorted[e + 0]);
        int s1 = __builtin_nontemporal_load(&src_sorted[e + 1]);
        int s2 = __builtin_nontemporal_load(&src_sorted[e + 2]);
        int s3 = __builtin_nontemporal_load(&src_sorted[e + 3]);
        unsigned int w0 = hsb[(size_t)s0 * 64 + c];
        unsigned int w1 = hsb[(size_t)s1 * 64 + c];
        unsigned int w2 = hsb[(size_t)s2 * 64 + c];
        unsigned int w3 = hsb[(size_t)s3 * 64 + c];
        ax += (bf_lo(w0) + bf_lo(w1)) + (bf_lo(w2) + bf_lo(w3));
        ay += (bf_hi(w0) + bf_hi(w1)) + (bf_hi(w2) + bf_hi(w3));
        e += 4;
    }
    for (; e < hi; ++e) {
        int s = __builtin_nontemporal_load(&src_sorted[e]);
        unsigned int ws = hsb[(size_t)s * 64 + c];
        ax += bf_lo(ws);
        ay += bf_hi(ws);
    }
    float di = dinv[i];
    float2 bb = *reinterpret_cast<const float2*>(&b1[2 * c]);
    float v0 = di * ax + bb.x;
    float v1 = di * ay + bb.y;
    unsigned int pv = pack_bf2(v0 > 0.f ? v0 : 0.f, v1 > 0.f ? v1 : 0.f);
    __builtin_nontemporal_store(pv, &h2b[(size_t)i * 64 + c]);
}

// out[i][2c..2c+1] = dinv[i]*(zsb_sum) + b2; 2 nodes per 64-thread block.
__global__ __launch_bounds__(64) void k_agg2(const unsigned int* __restrict__ zsb,
                                             const float* __restrict__ dinv,
                                             const int* __restrict__ row_ptr,
                                             const int* __restrict__ src_sorted,
                                             const float* __restrict__ b2,
                                             float* __restrict__ out, int n) {
    int i = blockIdx.x * 2 + (threadIdx.x >> 5);
    int c = threadIdx.x & 31;
    if (i >= n) return;
    unsigned int w = zsb[(size_t)i * 32 + c];
    float ax = bf_lo(w), ay = bf_hi(w);
    int lo = row_ptr[i], hi = row_ptr[i + 1];
    int e = lo;
    for (; e + 8 <= hi; e += 8) {
        int s0 = __builtin_nontemporal_load(&src_sorted[e + 0]);
        int s1 = __builtin_nontemporal_load(&src_sorted[e + 1]);
        int s2 = __builtin_nontemporal_load(&src_sorted[e + 2]);
        int s3 = __builtin_nontemporal_load(&src_sorted[e + 3]);
        int s4 = __builtin_nontemporal_load(&src_sorted[e + 4]);
        int s5 = __builtin_nontemporal_load(&src_sorted[e + 5]);
        int s6 = __builtin_nontemporal_load(&src_sorted[e + 6]);
        int s7 = __builtin_nontemporal_load(&src_sorted[e + 7]);
        unsigned int w0 = zsb[(size_t)s0 * 32 + c];
        unsigned int w1 = zsb[(size_t)s1 * 32 + c];
        unsigned int w2 = zsb[(size_t)s2 * 32 + c];
        unsigned int w3 = zsb[(size_t)s3 * 32 + c];
        unsigned int w4 = zsb[(size_t)s4 * 32 + c];
        unsigned int w5 = zsb[(size_t)s5 * 32 + c];
        unsigned int w6 = zsb[(size_t)s6 * 32 + c];
        unsigned int w7 = zsb[(size_t)s7 * 32 + c];
        ax += ((bf_lo(w0) + bf_lo(w1)) + (bf_lo(w2) + bf_lo(w3)))
            + ((bf_lo(w4) + bf_lo(w5)) + (bf_lo(w6) + bf_lo(w7)));
        ay += ((bf_hi(w0) + bf_hi(w1)) + (bf_hi(w2) + bf_hi(w3)))
            + ((bf_hi(w4) + bf_hi(w5)) + (bf_hi(w6) + bf_hi(w7)));
    }
    if (e + 4 <= hi) {
        int s0 = __builtin_nontemporal_load(&src_sorted[e + 0]);
        int s1 = __builtin_nontemporal_load(&src_sorted[e + 1]);
        int s2 = __builtin_nontemporal_load(&src_sorted[e + 2]);
        int s3 = __builtin_nontemporal_load(&src_sorted[e + 3]);
        unsigned int w0 = zsb[(size_t)s0 * 32 + c];
        unsigned int w1 = zsb[(size_t)s1 * 32 + c];
        unsigned int w2 = zsb[(size_t)s2 * 32 + c];
        unsigned int w3 = zsb[(size_t)s3 * 32 + c];
        ax += (bf_lo(w0) + bf_lo(w1)) + (bf_lo(w2) + bf_lo(w3));
        ay += (bf_hi(w0) + bf_hi(w1)) + (bf_hi(w2) + bf_hi(w3));
        e += 4;
    }
    for (; e < hi; ++e) {
        int s = __builtin_nontemporal_load(&src_sorted[e]);
        unsigned int ws = zsb[(size_t)s * 32 + c];
        ax += bf_lo(ws);
        ay += bf_hi(ws);
    }
    float di = dinv[i];
    float2 bb = *reinterpret_cast<const float2*>(&b2[2 * c]);
    float2 o = {di * ax + bb.x, di * ay + bb.y};
    *reinterpret_cast<float2*>(&out[(size_t)i * 64 + 2 * c]) = o;
}

// ---------------- launch ----------------

static inline size_t alignup(size_t v) { return (v + 255) & ~(size_t)255; }

extern "C" void kernel_launch(void* const* d_in, const int* in_sizes, int n_in,
                              void* d_out, int out_size, void* d_ws, size_t ws_size,
                              hipStream_t stream) {
    const float* x  = (const float*)d_in[0];
    const void*  ei = d_in[1];
    const float* W1 = (const float*)d_in[2];
    const float* b1 = (const float*)d_in[3];
    const float* W2 = (const float*)d_in[4];
    const float* b2 = (const float*)d_in[5];

    const int n = in_sizes[0] / 128;   // 100000
    const int e = in_sizes[1] / 2;     // 3200000

    char* p = (char*)d_ws;
    auto take = [&](size_t bytes) { char* q = p; p += alignup(bytes); return q; };
    size_t pairs_bytes = (size_t)e * 4;            // 12.8 MB
    size_t hsb_bytes   = (size_t)n * 64 * 4;       // 25.6 MB
    size_t regA_bytes  = pairs_bytes > hsb_bytes ? pairs_bytes : hsb_bytes;
    char* regA = (char*)take(regA_bytes);
    unsigned int* pairs = (unsigned int*)regA;     // dead before hsb written
    unsigned int* hsb   = (unsigned int*)regA;

    unsigned int* h2b        = (unsigned int*)take((size_t)n * 64 * 4);
    int*          is64       = (int*)  take(4);
    float*        dinv       = (float*)take((size_t)n * 4);
    int*          row_ptr    = (int*)  take((size_t)(n + 1) * 4);
    int*          bkt_cnt    = (int*)  take(512 * 4);
    int*          bkt_base   = (int*)  take(513 * 4);
    int*          bkt_cursor = (int*)  take(512 * 4);
    int*          src_sorted = (int*)  take((size_t)e * 4);
    unsigned int* zsb        = (unsigned int*)take((size_t)n * 32 * 4);
    if ((size_t)(p - (char*)d_ws) > ws_size) return;

    const int nb_bkt  = (n + 255) >> 8;
    const int nb_chnk = (e + BKT_CH - 1) / BKT_CH;

    k_detect64<<<1, 256, 0, stream>>>((const unsigned int*)ei, e, is64);
    k_zero512<<<1, 512, 0, stream>>>(bkt_cnt);
    k_hist<<<nb_chnk, 256, 0, stream>>>(ei, e, is64, bkt_cnt);
    k_scan_bkt<<<1, 512, 0, stream>>>(bkt_cnt, bkt_base, bkt_cursor, nb_bkt);
    k_bucket<<<nb_chnk, 256, 0, stream>>>(ei, e, is64, bkt_cursor, pairs);
    k_place_deg<<<nb_bkt, 256, 0, stream>>>(pairs, bkt_base, n, nb_bkt,
                                            row_ptr, dinv, src_sorted);

    k_gemm128<<<(n + 63) / 64, 256, 0, stream>>>(x, W1, dinv, hsb, n);
    k_agg1<<<n, 64, 0, stream>>>(hsb, dinv, row_ptr, src_sorted, b1, h2b);
    k_gemm64<<<(n + 63) / 64, 256, 0, stream>>>(h2b, W2, dinv, zsb, n);
    k_agg2<<<(n + 1) / 2, 64, 0, stream>>>(zsb, dinv, row_ptr, src_sorted, b2, (float*)d_out, n);
}